// Round 18
// baseline (259.469 us; speedup 1.0000x reference)
//
#include <hip/hip_runtime.h>

typedef _Float16 f16;
typedef _Float16 f16x4 __attribute__((ext_vector_type(4)));
typedef _Float16 f16x8 __attribute__((ext_vector_type(8)));
typedef float f32x4 __attribute__((ext_vector_type(4)));
typedef float f32x16 __attribute__((ext_vector_type(16)));
typedef unsigned u32;
typedef u32 u32x4 __attribute__((ext_vector_type(4)));

constexpr int Dd = 256;
constexpr long long QOFF     = 1;
constexpr long long PERP_OFF = 16777217LL;
constexpr long long ENC_OFF  = 16777218LL;
constexpr long long ENC_CNT  = 67108864LL;

__device__ inline f32x4 ntload4(const float* p) {
    return __builtin_nontemporal_load(reinterpret_cast<const f32x4*>(p));
}

// ---------------- K0: pack codebook (hi f16) into MFMA-A-fragment order + norms ----
// epk: kt(32)*16384 + dc(16)*1024 + lane(64)*16 + j*2
//   = f16( e[kt*32 + (lane&31)][dc*16 + (lane>>5)*8 + j] )
__global__ void prep_kernel(const float* __restrict__ emb, char* __restrict__ epk,
                            float* __restrict__ enorm) {
    const int t = threadIdx.x;
    const int k = blockIdx.x * 4 + (t >> 6);
    const int d4 = (t & 63) * 4;
    float4 v = *reinterpret_cast<const float4*>(emb + (size_t)k * Dd + d4);
    float s = v.x * v.x + v.y * v.y + v.z * v.z + v.w * v.w;
#pragma unroll
    for (int m = 1; m < 64; m <<= 1) s += __shfl_xor(s, m);
    float a[4] = {v.x, v.y, v.z, v.w};
    f16x4 h;
#pragma unroll
    for (int j = 0; j < 4; ++j) h[j] = (f16)a[j];
    const int kt = k >> 5, l31 = k & 31;
    const int dc = d4 >> 4, hb = (d4 >> 3) & 1, j0 = d4 & 7;
    const int lane = 32 * hb + l31;
    size_t off = (size_t)kt * 16384 + (size_t)dc * 1024 + lane * 16 + j0 * 2;
    *reinterpret_cast<f16x4*>(epk + off) = h;
    if ((t & 63) == 0) enorm[k] = s;
}

// ---------------- K0b: pack x (hi f16) into MFMA-B-fragment order (R9-verbatim) ----
// xpk: pt32(2048)*16384 + dc(16)*1024 + lane*16 + j*2
//   = f16( x[pt32*32 + (lane&31)][dc*16 + (lane>>5)*8 + j] )   (point n = b*1024+hw)
__global__ __launch_bounds__(256) void xprep_kernel(const float* __restrict__ in,
                                                    char* __restrict__ xpk) {
    __shared__ char lds[32768];  // [64 pts][256 d] f16, off=(p*512+d*2)^((p&15)<<4)
    const int t = threadIdx.x;
    const int n0 = blockIdx.x * 64;
    const int b = n0 >> 10, hw0 = n0 & 1023;
    const float* inb = in + (size_t)b * (Dd * 1024) + hw0;
    {
        const int c  = t & 15;
        const int g  = (t >> 4) & 3;
        const int hi = t >> 6;
        const int dp = hi * 4 + (g ^ (c >> 2));
        for (int it = 0; it < 8; ++it) {
            const int d = it * 32 + dp * 2;
            f32x4 v0 = ntload4(inb + (size_t)d * 1024 + c * 4);
            f32x4 v1 = ntload4(inb + (size_t)(d + 1) * 1024 + c * 4);
#pragma unroll
            for (int j = 0; j < 4; ++j) {
                int p = 4 * c + j;
                union { f16 h[2]; u32 u; } ph;
                ph.h[0] = (f16)v0[j]; ph.h[1] = (f16)v1[j];
                int off = (p * 512 + d * 2) ^ ((p & 15) << 4);
                *reinterpret_cast<u32*>(lds + off) = ph.u;
            }
        }
    }
    __syncthreads();
    char* outb = xpk + (size_t)n0 * 512;
    for (int it = 0; it < 8; ++it) {
        int fid = it * 256 + t;                  // out_off = fid*16 (linear!)
        int lane = fid & 63, dcl = (fid >> 6) & 15, ptl = fid >> 10;
        int p  = ptl * 32 + (lane & 31);
        int d0 = dcl * 16 + (lane >> 5) * 8;
        int off = (p * 512 + d0 * 2) ^ ((p & 15) << 4);
        u32x4 v = *reinterpret_cast<const u32x4*>(lds + off);
        __builtin_nontemporal_store(v, reinterpret_cast<u32x4*>(outb + (size_t)fid * 16));
    }
}

// ---------------- K1: argmin — e in regs, async gload_lds double-buffered staging --
// Grid 512, XCD-local decomposition (g = wgid>>7, pb = wgid&127).
// 8 waves; wave w owns codes (g*8+w)*32 .. +32 as 16 A-frags in VGPRs, loaded ONCE.
// Per chunk (64 pts = 32 KB): issue ch+1's global_load_lds (4/wave, linear,
// wave-uniform dest) into xbuf^1 BEFORE computing xbuf — latency hides under the
// 2x16 MFMA; __syncthreads drains vmcnt. LDS 72 KB -> 2 blocks/CU.
__global__ __launch_bounds__(512, 4) void argmin_kernel(
    const char* __restrict__ xpk, const char* __restrict__ epk,
    const float* __restrict__ enorm, float* __restrict__ gout)
{
    __shared__ char lds[73728];           // [0,64K) xbuf[2][32K]; [64K,72K) merge
    float* mb1 = reinterpret_cast<float*>(lds + 65536);   // [8][64]
    float* mb2 = reinterpret_cast<float*>(lds + 67584);
    int*   mi1 = reinterpret_cast<int*>(lds + 69632);
    int*   mi2 = reinterpret_cast<int*>(lds + 71680);

    const int t  = threadIdx.x;
    const int g  = blockIdx.x >> 7;       // XCD-local: same-pb blocks 128 apart
    const int pb = blockIdx.x & 127;
    const int n0 = pb * 512;

    const int lane = t & 63, w = t >> 6;
    const int l31 = lane & 31, hh = lane >> 5;
    const int kt = g * 8 + w;
    const int kb = kt * 32;

    // ---- codebook fragments into registers (once per kernel)
    f16x8 e[16];
    {
        const char* pe = epk + (size_t)kt * 16384 + lane * 16;
#pragma unroll
        for (int dc = 0; dc < 16; ++dc)
            e[dc] = *reinterpret_cast<const f16x8*>(pe + dc * 1024);
    }

    // async stage of chunk ch into buffer buf: wave w covers its 4 KB slice
#define ARG_STAGE(CH, BUF)                                                        \
    {                                                                             \
        const char* gsrc_ = xpk + (size_t)(n0 + (CH) * 64) * 512 + w * 4096 + lane * 16; \
        char* ldst_ = lds + (BUF) * 32768 + w * 4096;                             \
        _Pragma("unroll")                                                         \
        for (int i_ = 0; i_ < 4; ++i_) {                                          \
            __builtin_amdgcn_global_load_lds(                                     \
                (const __attribute__((address_space(1))) void*)(gsrc_ + i_ * 1024), \
                (__attribute__((address_space(3))) void*)(ldst_ + i_ * 1024),     \
                16, 0, 0);                                                        \
        }                                                                         \
    }

    ARG_STAGE(0, 0);
    __syncthreads();   // compiler drains vmcnt(0) before barrier -> buf0 ready

#pragma unroll 1
    for (int ch = 0; ch < 8; ++ch) {
        const int cur = ch & 1;
        const int nc = n0 + ch * 64;

        if (ch < 7) ARG_STAGE(ch + 1, cur ^ 1);   // async, hides under compute

        // ---- compute: 2 tiles x 16 MFMA, fold, flush per tile
#pragma unroll 1
        for (int tl = 0; tl < 2; ++tl) {
            f32x16 acc = (f32x16)(0.f);
            const int xbase = cur * 32768 + tl * 16384 + lane * 16;
#pragma unroll
            for (int dc = 0; dc < 16; ++dc) {
                f16x8 xh = *reinterpret_cast<const f16x8*>(lds + xbase + dc * 1024);
                acc = __builtin_amdgcn_mfma_f32_32x32x16_f16(e[dc], xh, acc, 0, 0, 0);
            }
            float bd1 = 3.4e38f, bd2 = 3.4e38f; int bi1 = 0, bi2 = 0;
#pragma unroll
            for (int rq = 0; rq < 4; ++rq) {   // C/D: col=lane&31, row=(r&3)+8(r>>2)+4hh
                float4 env = *reinterpret_cast<const float4*>(enorm + kb + 8 * rq + 4 * hh);
                float en4[4] = {env.x, env.y, env.z, env.w};
#pragma unroll
                for (int ri = 0; ri < 4; ++ri) {   // ascending k per lane
                    float s = fmaf(-2.0f, acc[rq * 4 + ri], en4[ri]);
                    int k = kb + 8 * rq + 4 * hh + ri;
                    if (s < bd1) { bd2 = bd1; bi2 = bi1; bd1 = s; bi1 = k; }
                    else if (s < bd2) { bd2 = s; bi2 = k; }
                }
            }
            {   // merge the two half-wave code sets (lanes l, l+32 share a point)
                float ob1 = __shfl_xor(bd1, 32); int oi1 = __shfl_xor(bi1, 32);
                float ob2 = __shfl_xor(bd2, 32); int oi2 = __shfl_xor(bi2, 32);
                if (ob1 < bd1 || (ob1 == bd1 && oi1 < bi1)) {
                    float nb2; int ni2;
                    if (bd1 < ob2 || (bd1 == ob2 && bi1 < oi2)) { nb2 = bd1; ni2 = bi1; }
                    else { nb2 = ob2; ni2 = oi2; }
                    bd1 = ob1; bi1 = oi1; bd2 = nb2; bi2 = ni2;
                } else if (ob1 < bd2 || (ob1 == bd2 && oi1 < bi2)) { bd2 = ob1; bi2 = oi1; }
            }
            if (hh == 0) {
                int s = w * 64 + tl * 32 + l31;
                mb1[s] = bd1; mb2[s] = bd2; mi1[s] = bi1; mi2[s] = bi2;
            }
        }
        __syncthreads();   // drains stage vmcnt (buf^1 ready) + mb visible

        // ---- cross-wave merge (t<64) -> gout
        if (t < 64) {
            float b1 = mb1[t], b2 = mb2[t]; int i1 = mi1[t], i2 = mi2[t];
#pragma unroll
            for (int ww = 1; ww < 8; ++ww) {
                int s = ww * 64 + t;
                float ob1 = mb1[s], ob2 = mb2[s]; int oi1 = mi1[s], oi2 = mi2[s];
                if (ob1 < b1 || (ob1 == b1 && oi1 < i1)) {
                    float nb2; int ni2;
                    if (b1 < ob2 || (b1 == ob2 && i1 < oi2)) { nb2 = b1; ni2 = i1; }
                    else { nb2 = ob2; ni2 = oi2; }
                    b1 = ob1; i1 = oi1; b2 = nb2; i2 = ni2;
                } else if (ob1 < b2 || (ob1 == b2 && oi1 < i2)) { b2 = ob1; i2 = oi1; }
            }
            f32x4 o;
            o[0] = b1; o[1] = b2;
            o[2] = __int_as_float(i1); o[3] = __int_as_float(i2);
            __builtin_nontemporal_store(
                o, reinterpret_cast<f32x4*>(gout + ((size_t)g * 65536 + nc + t) * 4));
        }
        __syncthreads();   // mb free for next compute
    }
#undef ARG_STAGE
}

// ---------------- K2: merge4 + exact refine + quantized + loss + counts + idx ------
__global__ __launch_bounds__(256) void quantref_kernel(
    const float* __restrict__ in, const float* __restrict__ emb,
    const float* __restrict__ enorm, const float* __restrict__ gout,
    int* __restrict__ idx_out, float* __restrict__ outq,
    float* __restrict__ partials, int* __restrict__ counts)
{
    __shared__ float red[2][4][64];
    __shared__ int rowsel[64];
    __shared__ float sred[4];
    const int t = threadIdx.x;
    const int p = t & 63, cq = t >> 6;
    const int n0 = blockIdx.x * 64;
    const int b = n0 >> 10, hw0 = n0 & 1023;

    // merge the 4 code-groups' top-2 (redundant across cq groups; L2-hot)
    int k0, k1;
    {
        f32x4 v0 = *reinterpret_cast<const f32x4*>(gout + (size_t)(n0 + p) * 4);
        float b1 = v0[0], b2 = v0[1];
        int i1 = __float_as_int(v0[2]), i2 = __float_as_int(v0[3]);
#pragma unroll
        for (int g = 1; g < 4; ++g) {
            f32x4 v = *reinterpret_cast<const f32x4*>(
                gout + ((size_t)g * 65536 + n0 + p) * 4);
            float c1 = v[0], c2 = v[1];
            int j1 = __float_as_int(v[2]), j2 = __float_as_int(v[3]);
            if (c1 < b1 || (c1 == b1 && j1 < i1)) {
                float nb2; int ni2;
                if (b1 < c2 || (b1 == c2 && i1 < j2)) { nb2 = b1; ni2 = i1; }
                else { nb2 = c2; ni2 = j2; }
                b2 = nb2; i2 = ni2; b1 = c1; i1 = j1;
            } else if (c1 < b2 || (c1 == b2 && j1 < i2)) {
                b2 = c1; i2 = j1;
            }
        }
        k0 = i1; k1 = i2;
    }

    const float* e0 = emb + (size_t)k0 * Dd + cq * 64;
    const float* e1 = emb + (size_t)k1 * Dd + cq * 64;
    const float* xb = in + (size_t)b * (Dd * 1024) + (size_t)(cq * 64) * 1024 + hw0 + p;

    float xr[64];
    float d0 = 0.f, d1 = 0.f;
#pragma unroll
    for (int c = 0; c < 64; c += 4) {
        float4 a0 = *reinterpret_cast<const float4*>(e0 + c);
        float4 a1 = *reinterpret_cast<const float4*>(e1 + c);
        xr[c + 0] = __builtin_nontemporal_load(xb + (size_t)(c + 0) * 1024);
        xr[c + 1] = __builtin_nontemporal_load(xb + (size_t)(c + 1) * 1024);
        xr[c + 2] = __builtin_nontemporal_load(xb + (size_t)(c + 2) * 1024);
        xr[c + 3] = __builtin_nontemporal_load(xb + (size_t)(c + 3) * 1024);
        d0 = fmaf(xr[c+3], a0.w, fmaf(xr[c+2], a0.z, fmaf(xr[c+1], a0.y, fmaf(xr[c+0], a0.x, d0))));
        d1 = fmaf(xr[c+3], a1.w, fmaf(xr[c+2], a1.z, fmaf(xr[c+1], a1.y, fmaf(xr[c+0], a1.x, d1))));
    }
    red[0][cq][p] = d0;
    red[1][cq][p] = d1;
    __syncthreads();
    if (t < 64) {
        float dot0 = (red[0][0][t] + red[0][1][t]) + (red[0][2][t] + red[0][3][t]);
        float dot1 = (red[1][0][t] + red[1][1][t]) + (red[1][2][t] + red[1][3][t]);
        float s0 = enorm[k0] - 2.f * dot0;
        float s1 = enorm[k1] - 2.f * dot1;
        int row = (s1 < s0 || (s1 == s0 && k1 < k0)) ? k1 : k0;
        rowsel[t] = row;
        idx_out[n0 + t] = row;
        atomicAdd(&counts[row], 1);
    }
    __syncthreads();

    const int row = rowsel[p];
    const float* erow = emb + (size_t)row * Dd + cq * 64;
    const size_t base = (size_t)b * (Dd * 1024) + (size_t)(cq * 64) * 1024 + hw0 + p;
    float ls = 0.f;
#pragma unroll
    for (int c = 0; c < 64; c += 4) {
        float4 ev = *reinterpret_cast<const float4*>(erow + c);
        float e4[4] = {ev.x, ev.y, ev.z, ev.w};
#pragma unroll
        for (int j = 0; j < 4; ++j) {
            size_t a = base + (size_t)(c + j) * 1024;
            __builtin_nontemporal_store(e4[j], outq + a);
            float df = e4[j] - xr[c + j];
            ls = fmaf(df, df, ls);
        }
    }
#pragma unroll
    for (int m = 1; m < 64; m <<= 1) ls += __shfl_xor(ls, m);
    if ((t & 63) == 0) sred[t >> 6] = ls;
    __syncthreads();
    if (t == 0) partials[blockIdx.x] = (sred[0] + sred[1]) + (sred[2] + sred[3]);
}

// ---------------- K3: one-hot encodings (256 MB fill) ----------------
__global__ void enc_kernel(const int* __restrict__ idx, float* __restrict__ enc) {
    const long long T = 16777215LL;
    long long gid    = (long long)blockIdx.x * 256 + threadIdx.x;
    long long stride = (long long)gridDim.x * 256;
    if (gid == 0) {
        enc[0] = (idx[0] == 0) ? 1.f : 0.f;
        enc[1] = (idx[0] == 1) ? 1.f : 0.f;
        enc[67108862LL] = (idx[65535] == 1022) ? 1.f : 0.f;
        enc[67108863LL] = (idx[65535] == 1023) ? 1.f : 0.f;
    }
    for (long long c = gid; c < T; c += stride) {
        long long rel = 2 + 4 * c;
        int n  = (int)(rel >> 10);
        int kk = (int)(rel & 1023);
        f32x4 v;
        if (kk <= 1020) {
            int iv = idx[n];
            v[0] = (kk     == iv) ? 1.f : 0.f;
            v[1] = (kk + 1 == iv) ? 1.f : 0.f;
            v[2] = (kk + 2 == iv) ? 1.f : 0.f;
            v[3] = (kk + 3 == iv) ? 1.f : 0.f;
        } else {
#pragma unroll
            for (int j = 0; j < 4; ++j) {
                long long rr = rel + j;
                int nn = (int)(rr >> 10);
                int kj = (int)(rr & 1023);
                v[j] = (idx[nn] == kj) ? 1.f : 0.f;
            }
        }
        __builtin_nontemporal_store(v, reinterpret_cast<f32x4*>(enc + rel));
    }
}

// ---------------- K4: finalize loss + perplexity ----------------
__global__ __launch_bounds__(1024) void fin_kernel(
    const int* __restrict__ counts, const float* __restrict__ partials,
    float* __restrict__ out)
{
    __shared__ float r1[16];
    __shared__ float r2[16];
    const int t = threadIdx.x;
    float pl = partials[t];
    float pv = (float)counts[t] * (1.0f / 65536.0f);
    float pp = pv * logf(pv + 1e-10f);
#pragma unroll
    for (int m = 1; m < 64; m <<= 1) {
        pl += __shfl_xor(pl, m);
        pp += __shfl_xor(pp, m);
    }
    if ((t & 63) == 0) { r1[t >> 6] = pl; r2[t >> 6] = pp; }
    __syncthreads();
    if (t == 0) {
        float s1 = 0.f, s2 = 0.f;
#pragma unroll
        for (int i = 0; i < 16; ++i) { s1 += r1[i]; s2 += r2[i]; }
        out[0]        = 0.25f * s1 / 16777216.0f;
        out[PERP_OFF] = expf(-s2);
    }
}

extern "C" void kernel_launch(void* const* d_in, const int* in_sizes, int n_in,
                              void* d_out, int out_size, void* d_ws, size_t ws_size,
                              hipStream_t stream) {
    const float* in  = (const float*)d_in[0];
    const float* emb = (const float*)d_in[1];
    float* out = (float*)d_out;

    char* ws = (char*)d_ws;
    int*   counts   = (int*)ws;                // 4 KB
    float* partials = (float*)(ws + 4096);     // 4 KB
    int*   idx      = (int*)(ws + 16384);      // 256 KB

    // Scratch carved from the tail of the 268 MB encodings output region;
    // all consumed (argmin/quantref) before enc_kernel overwrites it.
    //   xpk: 32 MB | gout: 4 MB | epk: 512 KB | enorm: 4 KB
    const size_t xpkB = 33554432, goutB = 4194304, epkB = 524288;
    const size_t tailBytes = xpkB + goutB + epkB + 4096;
    uintptr_t base = ((uintptr_t)(out + ENC_OFF + ENC_CNT) - tailBytes) & ~(uintptr_t)255;
    char*  xpk   = (char*)base;
    float* gout  = (float*)(base + xpkB);
    char*  epk   = (char*)(base + xpkB + goutB);
    float* enorm = (float*)(base + xpkB + goutB + epkB);

    (void)hipMemsetAsync(counts, 0, 4096, stream);
    prep_kernel<<<256, 256, 0, stream>>>(emb, epk, enorm);
    xprep_kernel<<<1024, 256, 0, stream>>>(in, xpk);
    argmin_kernel<<<512, 512, 0, stream>>>(xpk, epk, enorm, gout);
    quantref_kernel<<<1024, 256, 0, stream>>>(in, emb, enorm, gout, idx,
                                              out + QOFF, partials, counts);
    enc_kernel<<<8192, 256, 0, stream>>>(idx, out + ENC_OFF);
    fin_kernel<<<1, 1024, 0, stream>>>(counts, partials, out);
}

// Round 19
// 232.327 us; speedup vs baseline: 1.1168x; 1.1168x over previous
//
#include <hip/hip_runtime.h>

typedef _Float16 f16;
typedef _Float16 f16x4 __attribute__((ext_vector_type(4)));
typedef _Float16 f16x8 __attribute__((ext_vector_type(8)));
typedef float f32x4 __attribute__((ext_vector_type(4)));
typedef float f32x16 __attribute__((ext_vector_type(16)));
typedef unsigned u32;
typedef u32 u32x4 __attribute__((ext_vector_type(4)));

constexpr int Dd = 256;
constexpr long long QOFF     = 1;
constexpr long long PERP_OFF = 16777217LL;
constexpr long long ENC_OFF  = 16777218LL;
constexpr long long ENC_CNT  = 67108864LL;

__device__ inline f32x4 ntload4(const float* p) {
    return __builtin_nontemporal_load(reinterpret_cast<const f32x4*>(p));
}

// ---------------- K0: pack codebook (hi f16) into MFMA-A-fragment order + norms ----
// epk: kt(32)*16384 + dc(16)*1024 + lane(64)*16 + j*2
//   = f16( e[kt*32 + (lane&31)][dc*16 + (lane>>5)*8 + j] )
__global__ void prep_kernel(const float* __restrict__ emb, char* __restrict__ epk,
                            float* __restrict__ enorm) {
    const int t = threadIdx.x;
    const int k = blockIdx.x * 4 + (t >> 6);
    const int d4 = (t & 63) * 4;
    float4 v = *reinterpret_cast<const float4*>(emb + (size_t)k * Dd + d4);
    float s = v.x * v.x + v.y * v.y + v.z * v.z + v.w * v.w;
#pragma unroll
    for (int m = 1; m < 64; m <<= 1) s += __shfl_xor(s, m);
    float a[4] = {v.x, v.y, v.z, v.w};
    f16x4 h;
#pragma unroll
    for (int j = 0; j < 4; ++j) h[j] = (f16)a[j];
    const int kt = k >> 5, l31 = k & 31;
    const int dc = d4 >> 4, hb = (d4 >> 3) & 1, j0 = d4 & 7;
    const int lane = 32 * hb + l31;
    size_t off = (size_t)kt * 16384 + (size_t)dc * 1024 + lane * 16 + j0 * 2;
    *reinterpret_cast<f16x4*>(epk + off) = h;
    if ((t & 63) == 0) enorm[k] = s;
}

// ---------------- K0b: pack x (hi f16) into MFMA-B-fragment order (R9-verbatim) ----
// xpk: pt32(2048)*16384 + dc(16)*1024 + lane*16 + j*2
//   = f16( x[pt32*32 + (lane&31)][dc*16 + (lane>>5)*8 + j] )   (point n = b*1024+hw)
__global__ __launch_bounds__(256) void xprep_kernel(const float* __restrict__ in,
                                                    char* __restrict__ xpk) {
    __shared__ char lds[32768];  // [64 pts][256 d] f16, off=(p*512+d*2)^((p&15)<<4)
    const int t = threadIdx.x;
    const int n0 = blockIdx.x * 64;
    const int b = n0 >> 10, hw0 = n0 & 1023;
    const float* inb = in + (size_t)b * (Dd * 1024) + hw0;
    {
        const int c  = t & 15;
        const int g  = (t >> 4) & 3;
        const int hi = t >> 6;
        const int dp = hi * 4 + (g ^ (c >> 2));
        for (int it = 0; it < 8; ++it) {
            const int d = it * 32 + dp * 2;
            f32x4 v0 = ntload4(inb + (size_t)d * 1024 + c * 4);
            f32x4 v1 = ntload4(inb + (size_t)(d + 1) * 1024 + c * 4);
#pragma unroll
            for (int j = 0; j < 4; ++j) {
                int p = 4 * c + j;
                union { f16 h[2]; u32 u; } ph;
                ph.h[0] = (f16)v0[j]; ph.h[1] = (f16)v1[j];
                int off = (p * 512 + d * 2) ^ ((p & 15) << 4);
                *reinterpret_cast<u32*>(lds + off) = ph.u;
            }
        }
    }
    __syncthreads();
    char* outb = xpk + (size_t)n0 * 512;
    for (int it = 0; it < 8; ++it) {
        int fid = it * 256 + t;                  // out_off = fid*16 (linear!)
        int lane = fid & 63, dcl = (fid >> 6) & 15, ptl = fid >> 10;
        int p  = ptl * 32 + (lane & 31);
        int d0 = dcl * 16 + (lane >> 5) * 8;
        int off = (p * 512 + d0 * 2) ^ ((p & 15) << 4);
        u32x4 v = *reinterpret_cast<const u32x4*>(lds + off);
        __builtin_nontemporal_store(v, reinterpret_cast<u32x4*>(outb + (size_t)fid * 16));
    }
}

// ---------------- K1: argmin — e in regs, linear xpk staging, XCD-local groups ----
// Grid 512. Decomposition g = wgid>>7, pb = wgid&127: the 4 code-group blocks of a
// pb have wgids {pb, pb+128, pb+256, pb+384} == pb (mod 8) -> SAME XCD -> the 32 MB
// xpk stream is fetched into each XCD's L2 once and shared by all 4 groups.
// 8 waves; wave w owns codes (g*8+w)*32 .. +32 as 16 A-frags in VGPRs, loaded ONCE.
// Per chunk (64 pts = 32 KB fragment-layout): linear stage -> 2 tiles x 16 MFMA ->
// fold top-2 -> cross-wave merge -> gout. 40 KB LDS -> 2 blocks/CU.
__global__ __launch_bounds__(512, 4) void argmin_kernel(
    const char* __restrict__ xpk, const char* __restrict__ epk,
    const float* __restrict__ enorm, float* __restrict__ gout)
{
    __shared__ char lds[40960];           // [0,32K) xbuf (frag layout); [32K,40K) merge
    float* mb1 = reinterpret_cast<float*>(lds + 32768);   // [8][64]
    float* mb2 = reinterpret_cast<float*>(lds + 34816);
    int*   mi1 = reinterpret_cast<int*>(lds + 36864);
    int*   mi2 = reinterpret_cast<int*>(lds + 38912);

    const int t  = threadIdx.x;
    const int g  = blockIdx.x >> 7;       // XCD-local: same-pb blocks 128 apart
    const int pb = blockIdx.x & 127;
    const int n0 = pb * 512;

    const int lane = t & 63, w = t >> 6;
    const int l31 = lane & 31, hh = lane >> 5;
    const int kt = g * 8 + w;
    const int kb = kt * 32;

    // ---- codebook fragments into registers (once per kernel)
    f16x8 e[16];
    {
        const char* pe = epk + (size_t)kt * 16384 + lane * 16;
#pragma unroll
        for (int dc = 0; dc < 16; ++dc)
            e[dc] = *reinterpret_cast<const f16x8*>(pe + dc * 1024);
    }

#pragma unroll 1
    for (int ch = 0; ch < 8; ++ch) {
        const int nc = n0 + ch * 64;

        // ---- stage x chunk: pure linear 32 KB copy (fragment layout, coalesced)
        {
            const char* xsrc = xpk + (size_t)nc * 512;
#pragma unroll
            for (int i = 0; i < 4; ++i) {
                u32x4 v = __builtin_nontemporal_load(
                    reinterpret_cast<const u32x4*>(xsrc + (size_t)(i * 512 + t) * 16));
                *reinterpret_cast<u32x4*>(lds + (i * 512 + t) * 16) = v;
            }
        }
        __syncthreads();

        // ---- compute: 2 tiles x 16 MFMA, fold, flush per tile
#pragma unroll 1
        for (int tl = 0; tl < 2; ++tl) {
            f32x16 acc = (f32x16)(0.f);
            const int xbase = tl * 16384 + lane * 16;
#pragma unroll
            for (int dc = 0; dc < 16; ++dc) {
                f16x8 xh = *reinterpret_cast<const f16x8*>(lds + xbase + dc * 1024);
                acc = __builtin_amdgcn_mfma_f32_32x32x16_f16(e[dc], xh, acc, 0, 0, 0);
            }
            float bd1 = 3.4e38f, bd2 = 3.4e38f; int bi1 = 0, bi2 = 0;
#pragma unroll
            for (int rq = 0; rq < 4; ++rq) {   // C/D: col=lane&31, row=(r&3)+8(r>>2)+4hh
                float4 env = *reinterpret_cast<const float4*>(enorm + kb + 8 * rq + 4 * hh);
                float en4[4] = {env.x, env.y, env.z, env.w};
#pragma unroll
                for (int ri = 0; ri < 4; ++ri) {   // ascending k per lane
                    float s = fmaf(-2.0f, acc[rq * 4 + ri], en4[ri]);
                    int k = kb + 8 * rq + 4 * hh + ri;
                    if (s < bd1) { bd2 = bd1; bi2 = bi1; bd1 = s; bi1 = k; }
                    else if (s < bd2) { bd2 = s; bi2 = k; }
                }
            }
            {   // merge the two half-wave code sets (lanes l, l+32 share a point)
                float ob1 = __shfl_xor(bd1, 32); int oi1 = __shfl_xor(bi1, 32);
                float ob2 = __shfl_xor(bd2, 32); int oi2 = __shfl_xor(bi2, 32);
                if (ob1 < bd1 || (ob1 == bd1 && oi1 < bi1)) {
                    float nb2; int ni2;
                    if (bd1 < ob2 || (bd1 == ob2 && bi1 < oi2)) { nb2 = bd1; ni2 = bi1; }
                    else { nb2 = ob2; ni2 = oi2; }
                    bd1 = ob1; bi1 = oi1; bd2 = nb2; bi2 = ni2;
                } else if (ob1 < bd2 || (ob1 == bd2 && oi1 < bi2)) { bd2 = ob1; bi2 = oi1; }
            }
            if (hh == 0) {
                int s = w * 64 + tl * 32 + l31;
                mb1[s] = bd1; mb2[s] = bd2; mi1[s] = bi1; mi2[s] = bi2;
            }
        }
        __syncthreads();   // mb visible; xbuf consumed

        // ---- cross-wave merge (t<64) -> gout
        if (t < 64) {
            float b1 = mb1[t], b2 = mb2[t]; int i1 = mi1[t], i2 = mi2[t];
#pragma unroll
            for (int ww = 1; ww < 8; ++ww) {
                int s = ww * 64 + t;
                float ob1 = mb1[s], ob2 = mb2[s]; int oi1 = mi1[s], oi2 = mi2[s];
                if (ob1 < b1 || (ob1 == b1 && oi1 < i1)) {
                    float nb2; int ni2;
                    if (b1 < ob2 || (b1 == ob2 && i1 < oi2)) { nb2 = b1; ni2 = i1; }
                    else { nb2 = ob2; ni2 = oi2; }
                    b1 = ob1; i1 = oi1; b2 = nb2; i2 = ni2;
                } else if (ob1 < b2 || (ob1 == b2 && oi1 < i2)) { b2 = ob1; i2 = oi1; }
            }
            f32x4 o;
            o[0] = b1; o[1] = b2;
            o[2] = __int_as_float(i1); o[3] = __int_as_float(i2);
            __builtin_nontemporal_store(
                o, reinterpret_cast<f32x4*>(gout + ((size_t)g * 65536 + nc + t) * 4));
        }
        __syncthreads();
    }
}

// ---------------- K2: merge4 + exact refine + quantized + loss + counts + idx ------
__global__ __launch_bounds__(256) void quantref_kernel(
    const float* __restrict__ in, const float* __restrict__ emb,
    const float* __restrict__ enorm, const float* __restrict__ gout,
    int* __restrict__ idx_out, float* __restrict__ outq,
    float* __restrict__ partials, int* __restrict__ counts)
{
    __shared__ float red[2][4][64];
    __shared__ int rowsel[64];
    __shared__ float sred[4];
    const int t = threadIdx.x;
    const int p = t & 63, cq = t >> 6;
    const int n0 = blockIdx.x * 64;
    const int b = n0 >> 10, hw0 = n0 & 1023;

    // merge the 4 code-groups' top-2 (redundant across cq groups; L2-hot)
    int k0, k1;
    {
        f32x4 v0 = *reinterpret_cast<const f32x4*>(gout + (size_t)(n0 + p) * 4);
        float b1 = v0[0], b2 = v0[1];
        int i1 = __float_as_int(v0[2]), i2 = __float_as_int(v0[3]);
#pragma unroll
        for (int g = 1; g < 4; ++g) {
            f32x4 v = *reinterpret_cast<const f32x4*>(
                gout + ((size_t)g * 65536 + n0 + p) * 4);
            float c1 = v[0], c2 = v[1];
            int j1 = __float_as_int(v[2]), j2 = __float_as_int(v[3]);
            if (c1 < b1 || (c1 == b1 && j1 < i1)) {
                float nb2; int ni2;
                if (b1 < c2 || (b1 == c2 && i1 < j2)) { nb2 = b1; ni2 = i1; }
                else { nb2 = c2; ni2 = j2; }
                b2 = nb2; i2 = ni2; b1 = c1; i1 = j1;
            } else if (c1 < b2 || (c1 == b2 && j1 < i2)) {
                b2 = c1; i2 = j1;
            }
        }
        k0 = i1; k1 = i2;
    }

    const float* e0 = emb + (size_t)k0 * Dd + cq * 64;
    const float* e1 = emb + (size_t)k1 * Dd + cq * 64;
    const float* xb = in + (size_t)b * (Dd * 1024) + (size_t)(cq * 64) * 1024 + hw0 + p;

    float xr[64];
    float d0 = 0.f, d1 = 0.f;
#pragma unroll
    for (int c = 0; c < 64; c += 4) {
        float4 a0 = *reinterpret_cast<const float4*>(e0 + c);
        float4 a1 = *reinterpret_cast<const float4*>(e1 + c);
        xr[c + 0] = __builtin_nontemporal_load(xb + (size_t)(c + 0) * 1024);
        xr[c + 1] = __builtin_nontemporal_load(xb + (size_t)(c + 1) * 1024);
        xr[c + 2] = __builtin_nontemporal_load(xb + (size_t)(c + 2) * 1024);
        xr[c + 3] = __builtin_nontemporal_load(xb + (size_t)(c + 3) * 1024);
        d0 = fmaf(xr[c+3], a0.w, fmaf(xr[c+2], a0.z, fmaf(xr[c+1], a0.y, fmaf(xr[c+0], a0.x, d0))));
        d1 = fmaf(xr[c+3], a1.w, fmaf(xr[c+2], a1.z, fmaf(xr[c+1], a1.y, fmaf(xr[c+0], a1.x, d1))));
    }
    red[0][cq][p] = d0;
    red[1][cq][p] = d1;
    __syncthreads();
    if (t < 64) {
        float dot0 = (red[0][0][t] + red[0][1][t]) + (red[0][2][t] + red[0][3][t]);
        float dot1 = (red[1][0][t] + red[1][1][t]) + (red[1][2][t] + red[1][3][t]);
        float s0 = enorm[k0] - 2.f * dot0;
        float s1 = enorm[k1] - 2.f * dot1;
        int row = (s1 < s0 || (s1 == s0 && k1 < k0)) ? k1 : k0;
        rowsel[t] = row;
        idx_out[n0 + t] = row;
        atomicAdd(&counts[row], 1);
    }
    __syncthreads();

    const int row = rowsel[p];
    const float* erow = emb + (size_t)row * Dd + cq * 64;
    const size_t base = (size_t)b * (Dd * 1024) + (size_t)(cq * 64) * 1024 + hw0 + p;
    float ls = 0.f;
#pragma unroll
    for (int c = 0; c < 64; c += 4) {
        float4 ev = *reinterpret_cast<const float4*>(erow + c);
        float e4[4] = {ev.x, ev.y, ev.z, ev.w};
#pragma unroll
        for (int j = 0; j < 4; ++j) {
            size_t a = base + (size_t)(c + j) * 1024;
            __builtin_nontemporal_store(e4[j], outq + a);
            float df = e4[j] - xr[c + j];
            ls = fmaf(df, df, ls);
        }
    }
#pragma unroll
    for (int m = 1; m < 64; m <<= 1) ls += __shfl_xor(ls, m);
    if ((t & 63) == 0) sred[t >> 6] = ls;
    __syncthreads();
    if (t == 0) partials[blockIdx.x] = (sred[0] + sred[1]) + (sred[2] + sred[3]);
}

// ---------------- K3: one-hot encodings (256 MB fill) ----------------
__global__ void enc_kernel(const int* __restrict__ idx, float* __restrict__ enc) {
    const long long T = 16777215LL;
    long long gid    = (long long)blockIdx.x * 256 + threadIdx.x;
    long long stride = (long long)gridDim.x * 256;
    if (gid == 0) {
        enc[0] = (idx[0] == 0) ? 1.f : 0.f;
        enc[1] = (idx[0] == 1) ? 1.f : 0.f;
        enc[67108862LL] = (idx[65535] == 1022) ? 1.f : 0.f;
        enc[67108863LL] = (idx[65535] == 1023) ? 1.f : 0.f;
    }
    for (long long c = gid; c < T; c += stride) {
        long long rel = 2 + 4 * c;
        int n  = (int)(rel >> 10);
        int kk = (int)(rel & 1023);
        f32x4 v;
        if (kk <= 1020) {
            int iv = idx[n];
            v[0] = (kk     == iv) ? 1.f : 0.f;
            v[1] = (kk + 1 == iv) ? 1.f : 0.f;
            v[2] = (kk + 2 == iv) ? 1.f : 0.f;
            v[3] = (kk + 3 == iv) ? 1.f : 0.f;
        } else {
#pragma unroll
            for (int j = 0; j < 4; ++j) {
                long long rr = rel + j;
                int nn = (int)(rr >> 10);
                int kj = (int)(rr & 1023);
                v[j] = (idx[nn] == kj) ? 1.f : 0.f;
            }
        }
        __builtin_nontemporal_store(v, reinterpret_cast<f32x4*>(enc + rel));
    }
}

// ---------------- K4: finalize loss + perplexity ----------------
__global__ __launch_bounds__(1024) void fin_kernel(
    const int* __restrict__ counts, const float* __restrict__ partials,
    float* __restrict__ out)
{
    __shared__ float r1[16];
    __shared__ float r2[16];
    const int t = threadIdx.x;
    float pl = partials[t];
    float pv = (float)counts[t] * (1.0f / 65536.0f);
    float pp = pv * logf(pv + 1e-10f);
#pragma unroll
    for (int m = 1; m < 64; m <<= 1) {
        pl += __shfl_xor(pl, m);
        pp += __shfl_xor(pp, m);
    }
    if ((t & 63) == 0) { r1[t >> 6] = pl; r2[t >> 6] = pp; }
    __syncthreads();
    if (t == 0) {
        float s1 = 0.f, s2 = 0.f;
#pragma unroll
        for (int i = 0; i < 16; ++i) { s1 += r1[i]; s2 += r2[i]; }
        out[0]        = 0.25f * s1 / 16777216.0f;
        out[PERP_OFF] = expf(-s2);
    }
}

extern "C" void kernel_launch(void* const* d_in, const int* in_sizes, int n_in,
                              void* d_out, int out_size, void* d_ws, size_t ws_size,
                              hipStream_t stream) {
    const float* in  = (const float*)d_in[0];
    const float* emb = (const float*)d_in[1];
    float* out = (float*)d_out;

    char* ws = (char*)d_ws;
    int*   counts   = (int*)ws;                // 4 KB
    float* partials = (float*)(ws + 4096);     // 4 KB
    int*   idx      = (int*)(ws + 16384);      // 256 KB

    // Scratch carved from the tail of the 268 MB encodings output region;
    // all consumed (argmin/quantref) before enc_kernel overwrites it.
    //   xpk: 32 MB | gout: 4 MB | epk: 512 KB | enorm: 4 KB
    const size_t xpkB = 33554432, goutB = 4194304, epkB = 524288;
    const size_t tailBytes = xpkB + goutB + epkB + 4096;
    uintptr_t base = ((uintptr_t)(out + ENC_OFF + ENC_CNT) - tailBytes) & ~(uintptr_t)255;
    char*  xpk   = (char*)base;
    float* gout  = (float*)(base + xpkB);
    char*  epk   = (char*)(base + xpkB + goutB);
    float* enorm = (float*)(base + xpkB + goutB + epkB);

    (void)hipMemsetAsync(counts, 0, 4096, stream);
    prep_kernel<<<256, 256, 0, stream>>>(emb, epk, enorm);
    xprep_kernel<<<1024, 256, 0, stream>>>(in, xpk);
    argmin_kernel<<<512, 512, 0, stream>>>(xpk, epk, enorm, gout);
    quantref_kernel<<<1024, 256, 0, stream>>>(in, emb, enorm, gout, idx,
                                              out + QOFF, partials, counts);
    enc_kernel<<<8192, 256, 0, stream>>>(idx, out + ENC_OFF);
    fin_kernel<<<1, 1024, 0, stream>>>(counts, partials, out);
}